// Round 1
// baseline (317.169 us; speedup 1.0000x reference)
//
#include <hip/hip_runtime.h>

#define N_NODES 50000
#define N_EDGES 800000
#define F 64

// ---------------- K1: weighted out-degree (skip self-loops) ----------------
__global__ __launch_bounds__(256) void deg_kernel(const int* __restrict__ ei,
                                                  const float* __restrict__ ew,
                                                  float* __restrict__ deg) {
    int e = blockIdx.x * blockDim.x + threadIdx.x;
    if (e >= N_EDGES) return;
    int r = ei[e];
    int c = ei[N_EDGES + e];
    if (r != c) atomicAdd(&deg[r], ew[e]);
}

// ---------------- K2: dinv = deg>0 ? rsqrt(deg) : 0 ----------------
__global__ __launch_bounds__(256) void dinv_kernel(const float* __restrict__ deg,
                                                   float* __restrict__ dinv) {
    int n = blockIdx.x * blockDim.x + threadIdx.x;
    if (n >= N_NODES) return;
    float d = deg[n];
    dinv[n] = (d > 0.0f) ? rsqrtf(d) : 0.0f;
}

// ---------------- K3: S[col] += norm * x[row]  (one wave per edge) ----------------
__global__ __launch_bounds__(256) void scatter_kernel(const int* __restrict__ ei,
                                                      const float* __restrict__ ew,
                                                      const float* __restrict__ x,
                                                      const float* __restrict__ dinv,
                                                      float* S) {
    int e = blockIdx.x * 4 + (threadIdx.x >> 6);   // wave-uniform edge id
    int lane = threadIdx.x & 63;
    if (e >= N_EDGES) return;
    int r = ei[e];
    int c = ei[N_EDGES + e];
    if (r == c) return;                            // self-loops removed
    float nrm = -dinv[r] * ew[e] * dinv[c];
    float v = nrm * x[r * F + lane];               // 256B coalesced gather
    atomicAdd(&S[c * F + lane], v);                // 256B coalesced scatter-add
}

// ---------------- K4: fused GEMMs + gating + output projection ----------------
// A-tile = [x | S] (64 nodes x 128), W chunks staged 32 rows at a time.
// S lives in d_out; final output overwrites the same rows (block-exclusive).
__global__ __launch_bounds__(256) void fused_kernel(
    const float* __restrict__ x, float* sOut,
    const float* __restrict__ Wxz0, const float* __restrict__ Wxz1,
    const float* __restrict__ Wxh0, const float* __restrict__ Wxh1,
    const float* __restrict__ bxz, const float* __restrict__ bhz,
    const float* __restrict__ bxh, const float* __restrict__ bhh,
    const float* __restrict__ Wlin, const float* __restrict__ blin) {
    __shared__ float As[64][136];   // [node][k], k<64 = x, k>=64 = S  (34.8 KB)
    __shared__ float Wc[64][64];    // rows 0..31 = Wz chunk, 32..63 = Wh chunk (16 KB)

    const int t = threadIdx.x;
    const int n0 = blockIdx.x * 64;
    const int ti = t >> 4;          // 0..15 -> node group (4 nodes)
    const int tj = t & 15;          // 0..15 -> feature group (4 feats)

    // ---- stage A = [x | S] (coalesced float4, zero-fill OOB rows) ----
#pragma unroll
    for (int r = 0; r < 4; ++r) {
        int idx = r * 256 + t;
        int n = idx >> 4, kq = idx & 15;
        int gn = n0 + n;
        float4 vx = make_float4(0.f, 0.f, 0.f, 0.f);
        float4 vs = vx;
        if (gn < N_NODES) {
            vx = *(const float4*)&x[gn * F + kq * 4];
            vs = *(const float4*)&sOut[gn * F + kq * 4];
        }
        *(float4*)&As[n][kq * 4] = vx;
        *(float4*)&As[n][64 + kq * 4] = vs;
    }

    float zacc[4][4], hacc[4][4];
#pragma unroll
    for (int j = 0; j < 4; ++j) {
        float bz = bxz[tj * 4 + j] + bhz[tj * 4 + j];
        float bh = bxh[tj * 4 + j] + bhh[tj * 4 + j];
#pragma unroll
        for (int i = 0; i < 4; ++i) { zacc[i][j] = bz; hacc[i][j] = bh; }
    }

    // ---- z/h GEMMs over K=128 in 4 chunks of 32 ----
    for (int kc = 0; kc < 4; ++kc) {
        if (kc) __syncthreads();
        // stage W chunk: Wz rows [kc*32, kc*32+32) -> Wc[0..31], Wh -> Wc[32..63]
#pragma unroll
        for (int r = 0; r < 2; ++r) {
            int idx = r * 256 + t;          // 0..511
            int kk = idx >> 4;              // 0..31
            int kq = idx & 15;
            int kg = kc * 32 + kk;          // global k in 0..127
            const float* srcz = (kg < 64) ? (Wxz0 + kg * F) : (Wxz1 + (kg - 64) * F);
            const float* srch = (kg < 64) ? (Wxh0 + kg * F) : (Wxh1 + (kg - 64) * F);
            *(float4*)&Wc[kk][kq * 4]      = *(const float4*)(srcz + kq * 4);
            *(float4*)&Wc[32 + kk][kq * 4] = *(const float4*)(srch + kq * 4);
        }
        __syncthreads();
#pragma unroll
        for (int k4 = 0; k4 < 8; ++k4) {
            float a_[4][4];
#pragma unroll
            for (int i = 0; i < 4; ++i) {
                float4 v = *(const float4*)&As[ti * 4 + i][kc * 32 + k4 * 4];
                a_[i][0] = v.x; a_[i][1] = v.y; a_[i][2] = v.z; a_[i][3] = v.w;
            }
#pragma unroll
            for (int kk = 0; kk < 4; ++kk) {
                float4 bz = *(const float4*)&Wc[k4 * 4 + kk][tj * 4];
                float4 bh = *(const float4*)&Wc[32 + k4 * 4 + kk][tj * 4];
#pragma unroll
                for (int i = 0; i < 4; ++i) {
                    float a = a_[i][kk];
                    zacc[i][0] += a * bz.x; zacc[i][1] += a * bz.y;
                    zacc[i][2] += a * bz.z; zacc[i][3] += a * bz.w;
                    hacc[i][0] += a * bh.x; hacc[i][1] += a * bh.y;
                    hacc[i][2] += a * bh.z; hacc[i][3] += a * bh.w;
                }
            }
        }
    }

    // ---- gating: H = (1-sigmoid(z))*tanh(h); R = relu(H) ----
    float R_[4][4];
#pragma unroll
    for (int i = 0; i < 4; ++i)
#pragma unroll
        for (int j = 0; j < 4; ++j) {
            float zz = 1.0f / (1.0f + __expf(-zacc[i][j]));
            float hh = tanhf(hacc[i][j]);
            R_[i][j] = fmaxf((1.0f - zz) * hh, 0.0f);
        }

    __syncthreads();   // everyone done reading As / Wc
    // write R into As[0..63][0..63]; stage full Wlin into Wc
#pragma unroll
    for (int i = 0; i < 4; ++i) {
        float4 v = make_float4(R_[i][0], R_[i][1], R_[i][2], R_[i][3]);
        *(float4*)&As[ti * 4 + i][tj * 4] = v;
    }
#pragma unroll
    for (int r = 0; r < 4; ++r) {
        int idx = r * 256 + t;              // 0..1023
        int kk = idx >> 4, kq = idx & 15;   // 64 rows x 16 float4
        *(float4*)&Wc[kk][kq * 4] = *(const float4*)&Wlin[kk * F + kq * 4];
    }
    __syncthreads();

    // ---- out = R @ Wlin + blin ----
    float oacc[4][4];
#pragma unroll
    for (int j = 0; j < 4; ++j) {
        float bl = blin[tj * 4 + j];
#pragma unroll
        for (int i = 0; i < 4; ++i) oacc[i][j] = bl;
    }
#pragma unroll
    for (int k4 = 0; k4 < 16; ++k4) {
        float a_[4][4];
#pragma unroll
        for (int i = 0; i < 4; ++i) {
            float4 v = *(const float4*)&As[ti * 4 + i][k4 * 4];
            a_[i][0] = v.x; a_[i][1] = v.y; a_[i][2] = v.z; a_[i][3] = v.w;
        }
#pragma unroll
        for (int kk = 0; kk < 4; ++kk) {
            float4 b = *(const float4*)&Wc[k4 * 4 + kk][tj * 4];
#pragma unroll
            for (int i = 0; i < 4; ++i) {
                float a = a_[i][kk];
                oacc[i][0] += a * b.x; oacc[i][1] += a * b.y;
                oacc[i][2] += a * b.z; oacc[i][3] += a * b.w;
            }
        }
    }
#pragma unroll
    for (int i = 0; i < 4; ++i) {
        int gn = n0 + ti * 4 + i;
        if (gn < N_NODES) {
            float4 v = make_float4(oacc[i][0], oacc[i][1], oacc[i][2], oacc[i][3]);
            *(float4*)&sOut[gn * F + tj * 4] = v;
        }
    }
}

extern "C" void kernel_launch(void* const* d_in, const int* in_sizes, int n_in,
                              void* d_out, int out_size, void* d_ws, size_t ws_size,
                              hipStream_t stream) {
    const float* x    = (const float*)d_in[0];
    const int*   ei   = (const int*)d_in[1];
    const float* ew   = (const float*)d_in[2];
    const float* Wxz0 = (const float*)d_in[3];
    const float* Wxz1 = (const float*)d_in[4];
    const float* bxz  = (const float*)d_in[5];
    const float* bhz  = (const float*)d_in[8];
    const float* Wxh0 = (const float*)d_in[15];
    const float* Wxh1 = (const float*)d_in[16];
    const float* bxh  = (const float*)d_in[17];
    const float* bhh  = (const float*)d_in[20];
    const float* Wlin = (const float*)d_in[21];
    const float* blin = (const float*)d_in[22];
    float* outp = (float*)d_out;          // doubles as S accumulator
    float* deg  = (float*)d_ws;
    float* dinv = deg + N_NODES;

    hipMemsetAsync(d_ws, 0, N_NODES * sizeof(float), stream);
    hipMemsetAsync(d_out, 0, (size_t)N_NODES * F * sizeof(float), stream);

    deg_kernel<<<(N_EDGES + 255) / 256, 256, 0, stream>>>(ei, ew, deg);
    dinv_kernel<<<(N_NODES + 255) / 256, 256, 0, stream>>>(deg, dinv);
    scatter_kernel<<<N_EDGES / 4, 256, 0, stream>>>(ei, ew, x, dinv, outp);
    fused_kernel<<<(N_NODES + 63) / 64, 256, 0, stream>>>(
        x, outp, Wxz0, Wxz1, Wxh0, Wxh1, bxz, bhz, bxh, bhh, Wlin, blin);
}